// Round 8
// baseline (188.212 us; speedup 1.0000x reference)
//
#include <hip/hip_runtime.h>
#include <math.h>

// Problem constants
#define Bn    64
#define Cn    3
#define IMG   224
#define PLANE (IMG*IMG)      // 50176
#define C1    6
#define P1    110            // conv1(220) + maxpool2 -> 110
#define NVALID (106*106)     // 11236
#define Hh    32
#define Ww    64
#define UPR   10
#define UPT   10
#define Hg    (Hh*UPR)       // 320
#define Wg    (Ww*UPT)       // 640
#define POOLED_SIZE (Bn*Cn*Hh*Ww)   // 393216
#define WSTRIDE 152          // padded 150-float wsum slot

// k1 geometry: block = 1 wave = (strip s, chunk-pair cp, image b)
#define NSTRIP 14            // 14 strips x 16 conv cols = 224
#define NCP    14            // 14 chunk pairs x 2 chunks x 4 pooled rows = 112
#define NBLK1  (NSTRIP*NCP*Bn)   // 12544
#define XROW   24            // staged px per LDS row (16 + 7 halo + pad)
#define NROW   20            // staged rows (2 chunks x 8 + 4 overlap)

typedef unsigned short u16;
typedef unsigned long long ull;
typedef _Float16 h8v __attribute__((ext_vector_type(8)));   // 8 f16 MFMA frag
typedef float f4v __attribute__((ext_vector_type(4)));      // 16x16 MFMA acc

// workspace: wsum (64*152 f32) | wt (64*2 f32, fallback) | af (5*64*8 f16) | x4h
#define WSUM_F   ((size_t)Bn * WSTRIDE)        // 9728 floats
#define WT_OFF   WSUM_F                        // 9728
#define AF_OFF_F (WSUM_F + Bn*2)               // 9856 floats (byte 39424)
#define AF_U16   (5*64*8)                      // 2560 u16 = 5120 B
#define X4H_OFF_F (AF_OFF_F + AF_U16/2)        // 11136 floats (byte 44544, 16B ok)
#define X4B_U16  ((size_t)Bn * PLANE * 4)
#define WS_NEEDED ((size_t)X4H_OFF_F * 4 + X4B_U16 * 2)

__device__ __forceinline__ u16 f16b(float f) {
    union { _Float16 h; u16 u; } c; c.h = (_Float16)f; return c.u;
}
__device__ __forceinline__ float h2lo(unsigned v) {
    union { _Float16 h; u16 u; } c; c.u = (u16)(v & 0xffffu); return (float)c.h;
}
__device__ __forceinline__ float h2hi(unsigned v) {
    union { _Float16 h; u16 u; } c; c.u = (u16)(v >> 16); return (float)c.h;
}

// group-local broadcast: read lane (group_base + idx) of a 16-lane group
#define GSHFL(v, idx) __shfl((v), (lane & 48) + (idx), 64)

// -------------------------------------------------------------------------
// K0: prebuild per-lane MFMA A-fragments (weights, k = ic + 4*kx) into ws
// (kills the per-block A-build) + zero wsum. One tiny block.
// -------------------------------------------------------------------------
__global__ __launch_bounds__(256) void k0_prep(
    const float* __restrict__ w1, u16* __restrict__ af,
    float* __restrict__ wsum)
{
    const int tid = threadIdx.x;
    if (tid < 64) {
        const int n = tid & 15, g = tid >> 4;
        #pragma unroll
        for (int ky = 0; ky < 5; ++ky) {
            #pragma unroll
            for (int j = 0; j < 8; ++j) {
                const int k = g * 8 + j, ic = k & 3, kx = k >> 2;
                float w = 0.0f;
                if (n < C1 && ic < 3 && kx < 5)
                    w = w1[((n * 3 + ic) * 5 + ky) * 5 + kx];
                af[(ky * 64 + tid) * 8 + j] = f16b(w);
            }
        }
    }
    for (int i = tid; i < Bn * WSTRIDE; i += 256) wsum[i] = 0.0f;
}

// -------------------------------------------------------------------------
// K1 (single-wave blocks, barrier-light): each 64-thread block owns one
// (strip, chunk-pair, image): stages a 20x24px window fp32->f16 NHWC4 in
// LDS, packs its owned 16x16px to x4h, runs 2 chunks x 40 MFMA, pools,
// and atomicAdds 150 window-sums per chunk into per-image wsum[150].
// No cross-wave barriers; 12,544 independent waves, 4-5 deep per SIMD —
// tests the latency-convoy theory (R0-R7: 448-thr lockstep blocks, 59us).
// Atomic order jitter tolerated (R4 passed with identical wsum atomics).
// L = z*64 + b -> image b on XCD b%8 (matches k3's map).
// -------------------------------------------------------------------------
__global__ __launch_bounds__(64) void k1_conv(
    const float* __restrict__ x,      // (B,3,224,224)
    const u16*   __restrict__ af,     // prebuilt A-frags (5,64,8) f16
    const float* __restrict__ b1f,    // (6,)
    float* __restrict__ wsum,         // (64,152) zeroed accumulator
    u16* __restrict__ x4h,            // (B,224,224,4) f16 out
    int do_pack)
{
    __shared__ __attribute__((aligned(16))) u16 xs[NROW][XROW * 4];  // 3840 B
    __shared__ float sc[C1][4];       // colsum[oc][py]
    __shared__ float eL[C1][4][4];    // prefix sums S1..S4 (strip 0)
    __shared__ float eH[C1][4][4];    // suffix sums U1..U4 (strip 13)

    const int L    = blockIdx.x;          // 0..12543
    const int b    = L & 63;              // XCD = b%8 (round-robin dispatch)
    const int z    = L >> 6;              // 0..195
    const int cp   = z / NSTRIP;          // chunk pair 0..13
    const int s    = z - cp * NSTRIP;     // strip 0..13
    const int gy0  = cp * 16;             // first input row
    const int gx0  = s * 16;              // first conv col
    const int lane = threadIdx.x;
    const int n    = lane & 15;           // B col / C col (conv col in strip)
    const int g    = lane >> 4;           // K-group / C row-group

    const float* xb = x + (size_t)b * (Cn * PLANE);

    // ---- stage: 20 rows x 3 ch x 6 float4 = 360 items ----
    for (int i = lane; i < NROW * 3 * 6; i += 64) {
        const int r   = i / 18;
        const int rem = i - r * 18;
        const int ch  = rem / 6;
        const int qd  = rem - ch * 6;
        const int gy  = gy0 + r;
        const int gx  = gx0 + qd * 4;
        float4 v; v.x = v.y = v.z = v.w = 0.0f;
        if (gy < IMG && gx + 3 < IMG)
            v = *(const float4*)(xb + ch * PLANE + gy * IMG + gx);
        u16* d = &xs[r][qd * 16 + ch];    // u16 idx = px*4 + ch
        d[0]  = f16b(v.x);
        d[4]  = f16b(v.y);
        d[8]  = f16b(v.z);
        d[12] = f16b(v.w);
    }

    // ---- A-frags: 5 coalesced 16B loads + bias ----
    h8v a[5];
    #pragma unroll
    for (int ky = 0; ky < 5; ++ky)
        a[ky] = *(const h8v*)(af + (ky * 64 + lane) * 8);
    f4v binit;
    #pragma unroll
    for (int e = 0; e < 4; ++e) {
        const int oc = g * 4 + e;
        binit[e] = (oc < C1) ? b1f[oc] : 0.0f;
    }

    __syncthreads();   // single-wave barrier: cheap, orders LDS stage

    // ---- pack x4h: owned 16 rows x 16 px (2 uint4 stores per lane) ----
    if (do_pack) {
        const int row = lane >> 3, pp = lane & 7;
        u16* ob = x4h + (size_t)b * PLANE * 4;
        #pragma unroll
        for (int h2 = 0; h2 < 2; ++h2) {
            const int rr = row + h2 * 8;
            const int gy = gy0 + rr;                       // <= 223 always
            const uint4 v = *(const uint4*)&xs[rr][pp * 8];
            *(uint4*)(ob + ((size_t)gy * IMG + gx0 + pp * 2) * 4) = v;
        }
    }

    // ---- two chunks sequentially (acc regs reused) ----
    for (int chh = 0; chh < 2; ++chh) {
        const int chunk = cp * 2 + chh;

        f4v acc[8];
        #pragma unroll
        for (int q = 0; q < 8; ++q) acc[q] = binit;

        #pragma unroll
        for (int r = 0; r < 12; ++r) {
            const u16* bp = &xs[chh * 8 + r][(n + 2 * g) * 4];
            h8v bf;
            ((ull*)&bf)[0] = *(const ull*)bp;
            ((ull*)&bf)[1] = *(const ull*)(bp + 4);
            #pragma unroll
            for (int ky = 0; ky < 5; ++ky) {
                const int q = r - ky;
                if (q >= 0 && q < 8)
                    acc[q] = __builtin_amdgcn_mfma_f32_16x16x32_f16(
                        a[ky], bf, acc[q], 0, 0, 0);
            }
        }

        // maxpool 2x2 + edge capture + 8-col strip colsum
        #pragma unroll
        for (int py = 0; py < 4; ++py) {
            #pragma unroll
            for (int e = 0; e < 4; ++e) {
                float t = fmaxf(acc[2 * py][e], acc[2 * py + 1][e]);
                t = fmaxf(t, __shfl_xor(t, 1, 64));   // pair lanes = pooled col
                if (s == NSTRIP - 1 && n >= 12) t = 0.0f;  // junk cols 110,111
                const int oc = g * 4 + e;
                if (s == 0) {                          // pooled cols 0..3
                    const float c0 = GSHFL(t, 0), c1 = GSHFL(t, 2);
                    const float c2 = GSHFL(t, 4), c3 = GSHFL(t, 6);
                    const float S1 = c0, S2 = S1 + c1, S3 = S2 + c2, S4 = S3 + c3;
                    const float sv = (n == 0) ? S1 : (n == 1) ? S2
                                   : (n == 2) ? S3 : S4;
                    if (n < 4 && oc < C1) eL[oc][py][n] = sv;
                }
                if (s == NSTRIP - 1) {                 // pooled cols 106..109
                    const float d109 = GSHFL(t, 10), d108 = GSHFL(t, 8);
                    const float d107 = GSHFL(t, 6),  d106 = GSHFL(t, 4);
                    const float U1 = d109, U2 = U1 + d108, U3 = U2 + d107,
                                U4 = U3 + d106;
                    const float uv = (n == 0) ? U1 : (n == 1) ? U2
                                   : (n == 2) ? U3 : U4;
                    if (n < 4 && oc < C1) eH[oc][py][n] = uv;
                }
                float v = t;                           // strip row-sum
                v += __shfl_xor(v, 2, 64);
                v += __shfl_xor(v, 4, 64);
                v += __shfl_xor(v, 8, 64);
                if (n == 0 && oc < C1) sc[oc][py] = v;
            }
        }
        __syncthreads();

        // 150 slots -> atomicAdd into per-image wsum
        for (int t0 = lane; t0 < 150; t0 += 64) {
            const int oc  = t0 / 25;
            const int rem = t0 - oc * 25;
            const int ky  = rem / 5, kx = rem - ky * 5;
            float total = 0.0f;
            #pragma unroll
            for (int py = 0; py < 4; ++py) {
                const int y = chunk * 4 + py;
                const bool valid = (y < P1) && ((unsigned)(y - ky) <= 105u);
                if (valid) {
                    float v = sc[oc][py];
                    if (s == 0 && kx > 0)          v -= eL[oc][py][kx - 1];
                    if (s == NSTRIP - 1 && kx < 4) v -= eH[oc][py][3 - kx];
                    total += v;
                }
            }
            atomicAdd(&wsum[b * WSTRIDE + t0], total);
        }
        __syncthreads();   // protect sc/eL/eH reuse for second chunk
    }
}

// -------------------------------------------------------------------------
// K2 (fallback path only): wsum -> feat -> fc1+relu -> fc2+sigmoid*5 -> wt.
// -------------------------------------------------------------------------
__global__ __launch_bounds__(256) void k2_head(
    const float* __restrict__ wsum, const float* __restrict__ w2,
    const float* __restrict__ b2, const float* __restrict__ fc1w,
    const float* __restrict__ fc1b, const float* __restrict__ fc2w,
    const float* __restrict__ fc2b, float* __restrict__ wt_ws,
    float* __restrict__ out)
{
    const int b = blockIdx.x;
    const int tid = threadIdx.x;
    __shared__ float wsb[150];
    __shared__ float sfeat[16];
    __shared__ float sh[8];

    if (tid < 150) wsb[tid] = wsum[b * WSTRIDE + tid];
    __syncthreads();
    if (tid < 16) {
        float s = 0.0f;
        for (int j = 0; j < 150; ++j) s += w2[tid * 150 + j] * wsb[j];
        sfeat[tid] = b2[tid] + s * (1.0f / (float)NVALID);
    }
    __syncthreads();
    if (tid < 8) {
        float s = fc1b[tid];
        #pragma unroll
        for (int j = 0; j < 16; ++j) s += fc1w[tid * 16 + j] * sfeat[j];
        sh[tid] = fmaxf(s, 0.0f);
    }
    __syncthreads();
    if (tid < 2) {
        float s = fc2b[tid];
        #pragma unroll
        for (int j = 0; j < 8; ++j) s += fc2w[tid * 8 + j] * sh[j];
        float sig = (s >= 0.0f) ? (1.0f / (1.0f + expf(-s)))
                                : (expf(s) / (1.0f + expf(s)));
        const float wgt = 5.0f * sig;
        wt_ws[b * 2 + tid] = wgt;
        out[POOLED_SIZE + b * 2 + tid] = wgt;
    }
}

// -------------------------------------------------------------------------
// Clamp-coordinate sampling (equivalent to corner-clamp border mode).
// -------------------------------------------------------------------------
__device__ __forceinline__ void sample_coords(
    float gxn, float gyn, int& x0, int& y0, float& wx, float& wy)
{
    float ix = ((gxn + 1.0f) * (float)IMG - 1.0f) * 0.5f;
    float iy = ((gyn + 1.0f) * (float)IMG - 1.0f) * 0.5f;
    ix = fminf(fmaxf(ix, 0.0f), (float)(IMG - 1));
    iy = fminf(fmaxf(iy, 0.0f), (float)(IMG - 1));
    x0 = (int)ix; if (x0 > IMG - 2) x0 = IMG - 2;
    y0 = (int)iy; if (y0 > IMG - 2) y0 = IMG - 2;
    wx = ix - (float)x0;
    wy = iy - (float)y0;
}

// -------------------------------------------------------------------------
// K3 (f16 NHWC4, merged head): head from wsum (direct, no chunk loop),
// then chain-broken batched log-polar sampling + 10x10 avg pool.
// Only h==0 blocks write the weight output. XCD-affinity matches k1.
// -------------------------------------------------------------------------
__global__ __launch_bounds__(640) void k3_fused_head(
    const u16* __restrict__ x4h,      // (B,224,224,4) f16
    const float* __restrict__ ltp,
    const float* __restrict__ wsum,
    const float* __restrict__ w2,  const float* __restrict__ b2,
    const float* __restrict__ fc1w, const float* __restrict__ fc1b,
    const float* __restrict__ fc2w, const float* __restrict__ fc2b,
    float* __restrict__ out)
{
    __shared__ float part[3 * Wg];
    __shared__ float wsb[152];
    __shared__ float sfp[16][10];
    __shared__ float sfeat[16];
    __shared__ float sh[8];
    __shared__ float sWt[2];

    const int L = blockIdx.x;         // 0..2047
    const int q = L >> 3;             // 0..255
    const int h = q & 31;
    const int b = (L & 7) + 8 * (q >> 5);
    const int tid = threadIdx.x;

    // ---- head (redundant per block; L2-local) ----
    if (tid < 150) wsb[tid] = wsum[b * WSTRIDE + tid];
    __syncthreads();
    if (tid < 160) {                  // feat partials: oc x 10 groups of 15
        const int oc = tid / 10, gq = tid - (tid / 10) * 10;
        float s = 0.0f;
        #pragma unroll
        for (int j = 0; j < 15; ++j)
            s += w2[oc * 150 + gq * 15 + j] * wsb[gq * 15 + j];
        sfp[oc][gq] = s;
    }
    __syncthreads();
    if (tid < 16) {
        float s = 0.0f;
        #pragma unroll
        for (int g2 = 0; g2 < 10; ++g2) s += sfp[tid][g2];
        sfeat[tid] = b2[tid] + s * (1.0f / (float)NVALID);
    }
    __syncthreads();
    if (tid < 8) {
        float s = fc1b[tid];
        #pragma unroll
        for (int j = 0; j < 16; ++j) s += fc1w[tid * 16 + j] * sfeat[j];
        sh[tid] = fmaxf(s, 0.0f);
    }
    __syncthreads();
    if (tid < 2) {
        float s = fc2b[tid];
        #pragma unroll
        for (int j = 0; j < 8; ++j) s += fc2w[tid * 8 + j] * sh[j];
        const float sig = (s >= 0.0f) ? (1.0f / (1.0f + expf(-s)))
                                      : (expf(s) / (1.0f + expf(s)));
        const float wgt = 5.0f * sig;
        sWt[tid] = wgt;
        if (h == 0) out[POOLED_SIZE + b * 2 + tid] = wgt;   // 64 blocks only
    }
    __syncthreads();

    // ---- sampling ----
    const float w0 = sWt[0];
    const float w1 = sWt[1];
    const float l0 = ltp[b * 2 + 0];
    const float l1 = ltp[b * 2 + 1];
    const float start = logf(0.01f * w0);
    const float stop  = logf(0.6f  * w1);
    const float dr = stop - start;

    const float angle = 6.283185307179586f * (float)tid / (float)Wg;
    const float sn = __sinf(angle);
    const float cs = __cosf(angle);

    const u16* xb4 = x4h + (size_t)b * PLANE * 4;

    int xi[UPR], yi[UPR];
    float wxa[UPR], wya[UPR];
    #pragma unroll
    for (int i = 0; i < UPR; ++i) {
        const float ri = __expf(start + dr * ((float)(h * UPR + i)
                                              * (1.0f / (float)(Hg - 1))));
        sample_coords(ri * sn + l0, ri * cs + l1, xi[i], yi[i], wxa[i], wya[i]);
    }

    float acc0 = 0.0f, acc1 = 0.0f, acc2 = 0.0f;
    #pragma unroll
    for (int bb = 0; bb < 2; ++bb) {
        uint4 R0[5], R1[5];
        #pragma unroll
        for (int i = 0; i < 5; ++i) {           // 10 gathers in flight
            const int sI = bb * 5 + i;
            const u16* base = xb4 + ((size_t)(yi[sI] * IMG + xi[sI])) * 4;
            R0[i] = *(const uint4*)(base);
            R1[i] = *(const uint4*)(base + IMG * 4);
        }
        #pragma unroll
        for (int i = 0; i < 5; ++i) {
            const int sI = bb * 5 + i;
            const float wx = wxa[sI], wy = wya[sI];
            const float wx0 = 1.0f - wx, wy0 = 1.0f - wy;
            const float w00 = wx0 * wy0, w01 = wx * wy0;
            const float w10 = wx0 * wy,  w11 = wx * wy;
            acc0 += w00*h2lo(R0[i].x) + w01*h2lo(R0[i].z)
                  + w10*h2lo(R1[i].x) + w11*h2lo(R1[i].z);
            acc1 += w00*h2hi(R0[i].x) + w01*h2hi(R0[i].z)
                  + w10*h2hi(R1[i].x) + w11*h2hi(R1[i].z);
            acc2 += w00*h2lo(R0[i].y) + w01*h2lo(R0[i].w)
                  + w10*h2lo(R1[i].y) + w11*h2lo(R1[i].w);
        }
    }
    part[0 * Wg + tid] = acc0;
    part[1 * Wg + tid] = acc1;
    part[2 * Wg + tid] = acc2;
    __syncthreads();

    if (tid < Cn * Ww) {
        const int c = tid / Ww;
        const int w = tid % Ww;
        const float* p = part + c * Wg + w * UPT;
        float s = 0.0f;
        #pragma unroll
        for (int j = 0; j < UPT; ++j) s += p[j];
        out[(((size_t)b * Cn + c) * Hh + h) * Ww + w] = s * (1.0f / (UPR * UPT));
    }
}

// -------------------------------------------------------------------------
// K3 fallback (NCHW fp32 scalar gathers) — only if ws too small for x4h.
// -------------------------------------------------------------------------
__global__ __launch_bounds__(640) void k3_sample_pool_nchw(
    const float* __restrict__ x, const float* __restrict__ ltp,
    const float* __restrict__ wt, float* __restrict__ out)
{
    __shared__ float part[3 * Wg];
    const int L = blockIdx.x;
    const int q = L >> 3;
    const int h = q & 31;
    const int b = (L & 7) + 8 * (q >> 5);
    const int tid = threadIdx.x;

    const float w0 = wt[b * 2 + 0];
    const float w1 = wt[b * 2 + 1];
    const float l0 = ltp[b * 2 + 0];
    const float l1 = ltp[b * 2 + 1];
    const float start = logf(0.01f * w0);
    const float stop  = logf(0.6f  * w1);
    const float dr = stop - start;
    const float angle = 6.283185307179586f * (float)tid / (float)Wg;
    const float sn = __sinf(angle);
    const float cs = __cosf(angle);
    const float* xb = x + (size_t)b * Cn * PLANE;

    float acc0 = 0.0f, acc1 = 0.0f, acc2 = 0.0f;
    #pragma unroll
    for (int i = 0; i < UPR; ++i) {
        const float ri = __expf(start + dr * ((float)(h * UPR + i)
                                              * (1.0f / (float)(Hg - 1))));
        int x0, y0; float wx, wy;
        sample_coords(ri * sn + l0, ri * cs + l1, x0, y0, wx, wy);
        const float wx0 = 1.0f - wx, wy0 = 1.0f - wy;
        const float w00 = wx0 * wy0, w01 = wx * wy0;
        const float w10 = wx0 * wy,  w11 = wx * wy;
        const int o00 = y0 * IMG + x0;
        acc0 += w00*xb[o00] + w01*xb[o00+1] + w10*xb[o00+IMG] + w11*xb[o00+IMG+1];
        const float* x1p = xb + PLANE;
        acc1 += w00*x1p[o00] + w01*x1p[o00+1] + w10*x1p[o00+IMG] + w11*x1p[o00+IMG+1];
        const float* x2p = xb + 2 * PLANE;
        acc2 += w00*x2p[o00] + w01*x2p[o00+1] + w10*x2p[o00+IMG] + w11*x2p[o00+IMG+1];
    }
    part[0 * Wg + tid] = acc0;
    part[1 * Wg + tid] = acc1;
    part[2 * Wg + tid] = acc2;
    __syncthreads();

    if (tid < Cn * Ww) {
        const int c = tid / Ww;
        const int w = tid % Ww;
        const float* p = part + c * Wg + w * UPT;
        float s = 0.0f;
        #pragma unroll
        for (int j = 0; j < UPT; ++j) s += p[j];
        out[(((size_t)b * Cn + c) * Hh + h) * Ww + w] = s * (1.0f / (UPR * UPT));
    }
}

// -------------------------------------------------------------------------
extern "C" void kernel_launch(void* const* d_in, const int* in_sizes, int n_in,
                              void* d_out, int out_size, void* d_ws, size_t ws_size,
                              hipStream_t stream) {
    const float* x       = (const float*)d_in[0];
    const float* ltp     = (const float*)d_in[1];
    const float* conv1_w = (const float*)d_in[2];
    const float* conv1_b = (const float*)d_in[3];
    const float* conv2_w = (const float*)d_in[4];
    const float* conv2_b = (const float*)d_in[5];
    const float* fc1_w   = (const float*)d_in[6];
    const float* fc1_b   = (const float*)d_in[7];
    const float* fc2_w   = (const float*)d_in[8];
    const float* fc2_b   = (const float*)d_in[9];
    float* out = (float*)d_out;

    const int do_pack = (ws_size >= WS_NEEDED) ? 1 : 0;

    float* wsum  = (float*)d_ws;                  // 64*152
    float* wt_ws = wsum + WT_OFF;                 // 64*2 (fallback only)
    u16*   af    = (u16*)(wsum + AF_OFF_F);       // 5*64*8 f16
    u16*   x4h   = (u16*)(wsum + X4H_OFF_F);      // 16B-aligned

    k0_prep<<<dim3(1), dim3(256), 0, stream>>>(conv1_w, af, wsum);

    k1_conv<<<dim3(NBLK1), dim3(64), 0, stream>>>(
        x, af, conv1_b, wsum, x4h, do_pack);

    if (do_pack) {
        k3_fused_head<<<dim3(Hh * Bn), dim3(Wg), 0, stream>>>(
            x4h, ltp, wsum, conv2_w, conv2_b,
            fc1_w, fc1_b, fc2_w, fc2_b, out);
    } else {
        k2_head<<<dim3(Bn), dim3(256), 0, stream>>>(wsum, conv2_w, conv2_b,
                                                    fc1_w, fc1_b, fc2_w, fc2_b,
                                                    wt_ws, out);
        k3_sample_pool_nchw<<<dim3(Hh * Bn), dim3(Wg), 0, stream>>>(
            x, ltp, wt_ws, out);
    }
}

// Round 9
// 172.413 us; speedup vs baseline: 1.0916x; 1.0916x over previous
//
#include <hip/hip_runtime.h>
#include <math.h>

// Problem constants
#define Bn    64
#define Cn    3
#define IMG   224
#define PLANE (IMG*IMG)      // 50176
#define C1    6
#define P1    110            // conv1(220) + maxpool2 -> 110
#define NVALID (106*106)     // 11236
#define Hh    32
#define Ww    64
#define UPR   10
#define UPT   10
#define Hg    (Hh*UPR)       // 320
#define Wg    (Ww*UPT)       // 640
#define POOLED_SIZE (Bn*Cn*Hh*Ww)   // 393216
#define NCHUNK 28            // 28 chunks x 4 pooled rows = 112 >= 110
#define PSTRIDE 152          // padded 150-float partial slot
#define ROWB  (IMG*8)        // 1792 B: one NHWC4-f16 row
#define TPB1  448            // 7 waves: 14 strips / 7 = 2 each

typedef unsigned short u16;
typedef unsigned int u32;
typedef unsigned long long ull;
typedef _Float16 h8v __attribute__((ext_vector_type(8)));   // 8 f16 MFMA frag
typedef float f4v __attribute__((ext_vector_type(4)));      // 16x16 MFMA acc

// workspace: partials | wt (fallback) | af (5*64*8 f16) | x4h (f16 NHWC4)
#define PART_FLOATS ((size_t)Bn * NCHUNK * PSTRIDE)     // 272,384
#define AF_OFF_F    (PART_FLOATS + Bn * 2)              // 272,512
#define X4H_OFF_F   (AF_OFF_F + 1280)                   // 273,792 (byte%16==0)
#define X4B_U16     ((size_t)Bn * PLANE * 4)
#define WS_NEEDED   ((size_t)X4H_OFF_F * 4 + X4B_U16 * 2)

__device__ __forceinline__ unsigned hpack(float a, float b) {
    union { _Float16 h; u16 u; } x, y;
    x.h = (_Float16)a; y.h = (_Float16)b;
    return (unsigned)x.u | ((unsigned)y.u << 16);
}
__device__ __forceinline__ u16 f16b(float f) {
    union { _Float16 h; u16 u; } c; c.h = (_Float16)f; return c.u;
}
__device__ __forceinline__ float h2lo(unsigned v) {
    union { _Float16 h; u16 u; } c; c.u = (u16)(v & 0xffffu); return (float)c.h;
}
__device__ __forceinline__ float h2hi(unsigned v) {
    union { _Float16 h; u16 u; } c; c.u = (u16)(v >> 16); return (float)c.h;
}

// group-local broadcast: read lane (group_base + idx) of a 16-lane group
#define GSHFL(v, idx) __shfl((v), (lane & 48) + (idx), 64)

// -------------------------------------------------------------------------
// K0: prebuild per-lane MFMA A-fragments (weights, k = ic + 4*kx) into ws.
// -------------------------------------------------------------------------
__global__ __launch_bounds__(64) void k0_prep(
    const float* __restrict__ w1, u16* __restrict__ af)
{
    const int tid = threadIdx.x;
    const int n = tid & 15, g = tid >> 4;
    #pragma unroll
    for (int ky = 0; ky < 5; ++ky) {
        #pragma unroll
        for (int j = 0; j < 8; ++j) {
            const int k = g * 8 + j, ic = k & 3, kx = k >> 2;
            float w = 0.0f;
            if (n < C1 && ic < 3 && kx < 5)
                w = w1[((n * 3 + ic) * 5 + ky) * 5 + kx];
            af[(ky * 64 + tid) * 8 + j] = f16b(w);
        }
    }
}

// -------------------------------------------------------------------------
// KA: pure-streaming fp32 NCHW -> f16 NHWC4 pack (read 25.7MB, write 12.9MB
// at memcpy-class BW). 802,816 items (4px each), 3136 x 256 exact.
// -------------------------------------------------------------------------
__global__ __launch_bounds__(256) void kA_pack(
    const float* __restrict__ x, u16* __restrict__ x4h)
{
    const int i = blockIdx.x * 256 + threadIdx.x;   // 0..802815
    const int b  = i / (PLANE / 4);
    const int p4 = i - b * (PLANE / 4);
    const float* xb = x + (size_t)b * 3 * PLANE + p4 * 4;
    const float4 c0 = *(const float4*)(xb);
    const float4 c1 = *(const float4*)(xb + PLANE);
    const float4 c2 = *(const float4*)(xb + 2 * PLANE);
    uint4 W0, W1;
    W0.x = hpack(c0.x, c1.x);  W0.y = hpack(c2.x, 0.0f);
    W0.z = hpack(c0.y, c1.y);  W0.w = hpack(c2.y, 0.0f);
    W1.x = hpack(c0.z, c1.z);  W1.y = hpack(c2.z, 0.0f);
    W1.z = hpack(c0.w, c1.w);  W1.w = hpack(c2.w, 0.0f);
    u16* ob = x4h + ((size_t)b * PLANE + p4 * 4) * 4;
    *(uint4*)(ob)     = W0;
    *(uint4*)(ob + 8) = W1;
}

// -------------------------------------------------------------------------
// KB: conv1 via MFMA with ASYNC global->LDS staging (global_load_lds x16B).
// LDS tile = byte-identical contiguous copy of 12 x4h rows (21 x 1024B
// insts, 3 per wave) -> no VGPR round-trip, no cvt, no pack, ONE latency
// exposure per block (the barrier drain) instead of per-iteration chains.
// Conv/pool/window-sum body identical to R5 (verified). A-frags from k0.
// Grid dim3(Bn, NCHUNK): image b on XCD b%8 (matches kA writes + k3 reads).
// -------------------------------------------------------------------------
__global__ __launch_bounds__(TPB1) void kB_conv(
    const u16* __restrict__ x4h,      // (B,224,224,4) f16
    const u16* __restrict__ af,       // prebuilt A-frags (5,64,8) f16
    const float* __restrict__ b1f,    // (6,)
    float* __restrict__ partial)      // (B,28,PSTRIDE)
{
    __shared__ __attribute__((aligned(16))) unsigned char xs[12 * ROWB];
    __shared__ float rowR[7][C1][4];
    __shared__ float edgeLo[4][C1][4];
    __shared__ float edgeHi[4][C1][4];

    const int b     = blockIdx.x;
    const int chunk = blockIdx.y;
    const int tid   = threadIdx.x;
    const int wid   = tid >> 6;
    const int lane  = tid & 63;
    const int n     = lane & 15;
    const int g     = lane >> 4;
    const int gy0   = chunk * 8;

    // tail chunk 27: only 8 valid rows (gy 216..223); zero LDS rows 8..11
    const int nInst = (chunk == NCHUNK - 1) ? 14 : 21;   // 1024B insts
    if (chunk == NCHUNK - 1)
        *(uint4*)(xs + 8 * ROWB + tid * 16) = (uint4){0u, 0u, 0u, 0u};

    // issue async copies: wave w owns insts {3w, 3w+1, 3w+2}
    {
        const char* gbase = (const char*)x4h
                          + ((size_t)b * PLANE + (size_t)gy0 * IMG) * 8;
        #pragma unroll
        for (int k = 0; k < 3; ++k) {
            const int j = wid * 3 + k;            // wave-uniform
            if (j < nInst) {
                const char* gp = gbase + j * 1024 + lane * 16;
                __builtin_amdgcn_global_load_lds(
                    (const __attribute__((address_space(1))) u32*)gp,
                    (__attribute__((address_space(3))) u32*)(xs + j * 1024),
                    16, 0, 0);
            }
        }
    }

    // A-frags (coalesced 16B loads, overlap with in-flight copies) + bias
    h8v a[5];
    #pragma unroll
    for (int ky = 0; ky < 5; ++ky)
        a[ky] = *(const h8v*)(af + (ky * 64 + lane) * 8);
    f4v binit;
    #pragma unroll
    for (int e = 0; e < 4; ++e) {
        const int oc = g * 4 + e;
        binit[e] = (oc < C1) ? b1f[oc] : 0.0f;
    }

    __syncthreads();   // drains vmcnt -> xs ready

    float colsum[4][4];
    #pragma unroll
    for (int py = 0; py < 4; ++py)
        #pragma unroll
        for (int e = 0; e < 4; ++e) colsum[py][e] = 0.0f;

    #pragma unroll
    for (int si = 0; si < 2; ++si) {
        const int s = wid * 2 + si;         // strip: conv cols s*16..s*16+15
        const unsigned sByte = (unsigned)(s * 128 + n * 8 + g * 16);

        f4v acc[8];
        #pragma unroll
        for (int q = 0; q < 8; ++q) acc[q] = binit;

        #pragma unroll
        for (int r = 0; r < 12; ++r) {
            h8v bf;
            const unsigned char* bp = xs + r * ROWB + sByte;
            ((ull*)&bf)[0] = *(const ull*)bp;
            ((ull*)&bf)[1] = *(const ull*)(bp + 8);
            #pragma unroll
            for (int ky = 0; ky < 5; ++ky) {
                const int q = r - ky;
                if (q >= 0 && q < 8)
                    acc[q] = __builtin_amdgcn_mfma_f32_16x16x32_f16(
                        a[ky], bf, acc[q], 0, 0, 0);
            }
        }

        // maxpool 2x2 + edge capture + col accumulation
        #pragma unroll
        for (int py = 0; py < 4; ++py) {
            #pragma unroll
            for (int e = 0; e < 4; ++e) {
                float t = fmaxf(acc[2 * py][e], acc[2 * py + 1][e]);
                t = fmaxf(t, __shfl_xor(t, 1, 64));
                if (s == 13 && n >= 12) t = 0.0f;     // junk cols 110,111
                colsum[py][e] += t;
                const int oc = g * 4 + e;
                if (s == 0) {                          // pooled cols 0..3
                    const float c0 = GSHFL(t, 0), c1 = GSHFL(t, 2);
                    const float c2 = GSHFL(t, 4), c3 = GSHFL(t, 6);
                    const float S1 = c0, S2 = S1 + c1, S3 = S2 + c2, S4 = S3 + c3;
                    const float sv = (n == 0) ? S1 : (n == 1) ? S2
                                   : (n == 2) ? S3 : S4;
                    if (n < 4 && oc < C1) edgeLo[py][oc][n] = sv;
                }
                if (s == 13) {                         // pooled cols 106..109
                    const float d109 = GSHFL(t, 10), d108 = GSHFL(t, 8);
                    const float d107 = GSHFL(t, 6),  d106 = GSHFL(t, 4);
                    const float U1 = d109, U2 = U1 + d108, U3 = U2 + d107,
                                U4 = U3 + d106;
                    const float uv = (n == 0) ? U1 : (n == 1) ? U2
                                   : (n == 2) ? U3 : U4;
                    if (n < 4 && oc < C1) edgeHi[py][oc][n] = uv;
                }
            }
        }
    }

    // per-wave row sums
    #pragma unroll
    for (int py = 0; py < 4; ++py) {
        #pragma unroll
        for (int e = 0; e < 4; ++e) {
            float v = colsum[py][e];
            v += __shfl_xor(v, 2, 64);
            v += __shfl_xor(v, 4, 64);
            v += __shfl_xor(v, 8, 64);
            const int oc = g * 4 + e;
            if (n == 0 && oc < C1) rowR[wid][oc][py] = v;
        }
    }
    __syncthreads();

    // final: slot(oc,ky,kx) = sum_py valid(py,ky) * (rowsum - S_kx - U_{4-kx})
    if (tid < 150) {
        const int oc = tid / 25;
        const int rem = tid - oc * 25;
        const int ky = rem / 5, kx = rem - ky * 5;
        float total = 0.0f;
        #pragma unroll
        for (int py = 0; py < 4; ++py) {
            const int y = chunk * 4 + py;
            const bool valid = (y < P1) && ((unsigned)(y - ky) <= 105u);
            float v = rowR[0][oc][py] + rowR[1][oc][py] + rowR[2][oc][py]
                    + rowR[3][oc][py] + rowR[4][oc][py] + rowR[5][oc][py]
                    + rowR[6][oc][py];
            if (kx > 0) v -= edgeLo[py][oc][kx - 1];
            if (kx < 4) v -= edgeHi[py][oc][3 - kx];
            total += valid ? v : 0.0f;
        }
        partial[((size_t)b * NCHUNK + chunk) * PSTRIDE + tid] = total;
    }
}

// -------------------------------------------------------------------------
// Clamp-coordinate sampling (equivalent to corner-clamp border mode).
// -------------------------------------------------------------------------
__device__ __forceinline__ void sample_coords(
    float gxn, float gyn, int& x0, int& y0, float& wx, float& wy)
{
    float ix = ((gxn + 1.0f) * (float)IMG - 1.0f) * 0.5f;
    float iy = ((gyn + 1.0f) * (float)IMG - 1.0f) * 0.5f;
    ix = fminf(fmaxf(ix, 0.0f), (float)(IMG - 1));
    iy = fminf(fmaxf(iy, 0.0f), (float)(IMG - 1));
    x0 = (int)ix; if (x0 > IMG - 2) x0 = IMG - 2;
    y0 = (int)iy; if (y0 > IMG - 2) y0 = IMG - 2;
    wx = ix - (float)x0;
    wy = iy - (float)y0;
}

// -------------------------------------------------------------------------
// K3 (f16 NHWC4, merged head, R7 structure): head from partials (parallel
// feat split; only h==0 blocks store weight), then chain-broken batched
// log-polar sampling + 10x10 avg pool. XCD-affinity matches kA/kB.
// -------------------------------------------------------------------------
__global__ __launch_bounds__(640) void k3_fused_head(
    const u16* __restrict__ x4h,      // (B,224,224,4) f16
    const float* __restrict__ ltp,
    const float* __restrict__ partial,
    const float* __restrict__ w2,  const float* __restrict__ b2,
    const float* __restrict__ fc1w, const float* __restrict__ fc1b,
    const float* __restrict__ fc2w, const float* __restrict__ fc2b,
    float* __restrict__ out)
{
    __shared__ float part[3 * Wg];
    __shared__ float wsb[152];
    __shared__ float sfp[16][10];
    __shared__ float sfeat[16];
    __shared__ float sh[8];
    __shared__ float sWt[2];

    const int L = blockIdx.x;         // 0..2047
    const int q = L >> 3;             // 0..255
    const int h = q & 31;
    const int b = (L & 7) + 8 * (q >> 5);
    const int tid = threadIdx.x;

    // ---- head (redundant per block; L2-local) ----
    if (tid < 150) {
        const float* p = partial + (size_t)b * NCHUNK * PSTRIDE + tid;
        float s = 0.0f;
        #pragma unroll
        for (int c = 0; c < NCHUNK; ++c) s += p[c * PSTRIDE];
        wsb[tid] = s;
    }
    __syncthreads();
    if (tid < 160) {                  // feat partials: oc x 10 groups of 15
        const int oc = tid / 10, gq = tid - (tid / 10) * 10;
        float s = 0.0f;
        #pragma unroll
        for (int j = 0; j < 15; ++j)
            s += w2[oc * 150 + gq * 15 + j] * wsb[gq * 15 + j];
        sfp[oc][gq] = s;
    }
    __syncthreads();
    if (tid < 16) {
        float s = 0.0f;
        #pragma unroll
        for (int g2 = 0; g2 < 10; ++g2) s += sfp[tid][g2];
        sfeat[tid] = b2[tid] + s * (1.0f / (float)NVALID);
    }
    __syncthreads();
    if (tid < 8) {
        float s = fc1b[tid];
        #pragma unroll
        for (int j = 0; j < 16; ++j) s += fc1w[tid * 16 + j] * sfeat[j];
        sh[tid] = fmaxf(s, 0.0f);
    }
    __syncthreads();
    if (tid < 2) {
        float s = fc2b[tid];
        #pragma unroll
        for (int j = 0; j < 8; ++j) s += fc2w[tid * 8 + j] * sh[j];
        const float sig = (s >= 0.0f) ? (1.0f / (1.0f + expf(-s)))
                                      : (expf(s) / (1.0f + expf(s)));
        const float wgt = 5.0f * sig;
        sWt[tid] = wgt;
        if (h == 0) out[POOLED_SIZE + b * 2 + tid] = wgt;   // 64 blocks only
    }
    __syncthreads();

    // ---- sampling ----
    const float w0 = sWt[0];
    const float w1 = sWt[1];
    const float l0 = ltp[b * 2 + 0];
    const float l1 = ltp[b * 2 + 1];
    const float start = logf(0.01f * w0);
    const float stop  = logf(0.6f  * w1);
    const float dr = stop - start;

    const float angle = 6.283185307179586f * (float)tid / (float)Wg;
    const float sn = __sinf(angle);
    const float cs = __cosf(angle);

    const u16* xb4 = x4h + (size_t)b * PLANE * 4;

    int xi[UPR], yi[UPR];
    float wxa[UPR], wya[UPR];
    #pragma unroll
    for (int i = 0; i < UPR; ++i) {
        const float ri = __expf(start + dr * ((float)(h * UPR + i)
                                              * (1.0f / (float)(Hg - 1))));
        sample_coords(ri * sn + l0, ri * cs + l1, xi[i], yi[i], wxa[i], wya[i]);
    }

    float acc0 = 0.0f, acc1 = 0.0f, acc2 = 0.0f;
    #pragma unroll
    for (int bb = 0; bb < 2; ++bb) {
        uint4 R0[5], R1[5];
        #pragma unroll
        for (int i = 0; i < 5; ++i) {           // 10 gathers in flight
            const int sI = bb * 5 + i;
            const u16* base = xb4 + ((size_t)(yi[sI] * IMG + xi[sI])) * 4;
            R0[i] = *(const uint4*)(base);
            R1[i] = *(const uint4*)(base + IMG * 4);
        }
        #pragma unroll
        for (int i = 0; i < 5; ++i) {
            const int sI = bb * 5 + i;
            const float wx = wxa[sI], wy = wya[sI];
            const float wx0 = 1.0f - wx, wy0 = 1.0f - wy;
            const float w00 = wx0 * wy0, w01 = wx * wy0;
            const float w10 = wx0 * wy,  w11 = wx * wy;
            acc0 += w00*h2lo(R0[i].x) + w01*h2lo(R0[i].z)
                  + w10*h2lo(R1[i].x) + w11*h2lo(R1[i].z);
            acc1 += w00*h2hi(R0[i].x) + w01*h2hi(R0[i].z)
                  + w10*h2hi(R1[i].x) + w11*h2hi(R1[i].z);
            acc2 += w00*h2lo(R0[i].y) + w01*h2lo(R0[i].w)
                  + w10*h2lo(R1[i].y) + w11*h2lo(R1[i].w);
        }
    }
    part[0 * Wg + tid] = acc0;
    part[1 * Wg + tid] = acc1;
    part[2 * Wg + tid] = acc2;
    __syncthreads();

    if (tid < Cn * Ww) {
        const int c = tid / Ww;
        const int w = tid % Ww;
        const float* p = part + c * Wg + w * UPT;
        float s = 0.0f;
        #pragma unroll
        for (int j = 0; j < UPT; ++j) s += p[j];
        out[(((size_t)b * Cn + c) * Hh + h) * Ww + w] = s * (1.0f / (UPR * UPT));
    }
}

// -------------------------------------------------------------------------
// Fallback path (ws too small for x4h): R6-style fp32-staged conv + head +
// fp32 NCHW sampling. Functional, not perf-critical.
// -------------------------------------------------------------------------
__global__ __launch_bounds__(TPB1) void k1_legacy(
    const float* __restrict__ x, const float* __restrict__ w1,
    const float* __restrict__ b1, float* __restrict__ partial)
{
    __shared__ __attribute__((aligned(16))) unsigned char xs[12 * ROWB + 128];
    __shared__ __attribute__((aligned(16))) _Float16 sa[5][64][8];
    __shared__ float rowR[7][C1][4];
    __shared__ float edgeLo[4][C1][4];
    __shared__ float edgeHi[4][C1][4];

    const int b     = blockIdx.x;
    const int chunk = blockIdx.y;
    const int tid   = threadIdx.x;
    const int wid   = tid >> 6;
    const int lane  = tid & 63;
    const int n     = lane & 15;
    const int g     = lane >> 4;
    const int gy0   = chunk * 8;
    const float* xb = x + (size_t)b * (Cn * PLANE);

    if (wid == 0) {
        #pragma unroll
        for (int ky = 0; ky < 5; ++ky) {
            #pragma unroll
            for (int j = 0; j < 8; ++j) {
                const int kmem = g * 8 + j;
                const int ic = kmem & 3, kx = kmem >> 2;
                float w = 0.0f;
                if (n < C1 && ic < 3 && kx < 5)
                    w = w1[((n * 3 + ic) * 5 + ky) * 5 + kx];
                sa[ky][lane][j] = (_Float16)w;
            }
        }
    } else {
        for (int i = tid - 64; i < 12 * 112; i += TPB1 - 64) {
            const int r = i / 112;
            const int p = i - r * 112;
            const int gy = gy0 + r;
            uint4 U; U.x = U.y = U.z = U.w = 0u;
            if (gy < IMG) {
                const float2 v0 = *(const float2*)(xb + 0 * PLANE + gy * IMG + 2 * p);
                const float2 v1 = *(const float2*)(xb + 1 * PLANE + gy * IMG + 2 * p);
                const float2 v2 = *(const float2*)(xb + 2 * PLANE + gy * IMG + 2 * p);
                U.x = hpack(v0.x, v1.x);
                U.y = hpack(v2.x, 0.0f);
                U.z = hpack(v0.y, v1.y);
                U.w = hpack(v2.y, 0.0f);
            }
            *(uint4*)(xs + r * ROWB + p * 16) = U;
        }
    }
    __syncthreads();

    h8v a[5];
    #pragma unroll
    for (int ky = 0; ky < 5; ++ky) a[ky] = *(const h8v*)&sa[ky][lane][0];
    f4v binit;
    #pragma unroll
    for (int e = 0; e < 4; ++e) {
        const int oc = g * 4 + e;
        binit[e] = (oc < C1) ? b1[oc] : 0.0f;
    }

    float colsum[4][4];
    #pragma unroll
    for (int py = 0; py < 4; ++py)
        #pragma unroll
        for (int e = 0; e < 4; ++e) colsum[py][e] = 0.0f;

    #pragma unroll
    for (int si = 0; si < 2; ++si) {
        const int s = wid * 2 + si;
        const unsigned sByte = (unsigned)(s * 128 + n * 8 + g * 16);
        f4v acc[8];
        #pragma unroll
        for (int q = 0; q < 8; ++q) acc[q] = binit;
        #pragma unroll
        for (int r = 0; r < 12; ++r) {
            h8v bf;
            const unsigned char* bp = xs + r * ROWB + sByte;
            ((ull*)&bf)[0] = *(const ull*)bp;
            ((ull*)&bf)[1] = *(const ull*)(bp + 8);
            #pragma unroll
            for (int ky = 0; ky < 5; ++ky) {
                const int q = r - ky;
                if (q >= 0 && q < 8)
                    acc[q] = __builtin_amdgcn_mfma_f32_16x16x32_f16(
                        a[ky], bf, acc[q], 0, 0, 0);
            }
        }
        #pragma unroll
        for (int py = 0; py < 4; ++py) {
            #pragma unroll
            for (int e = 0; e < 4; ++e) {
                float t = fmaxf(acc[2 * py][e], acc[2 * py + 1][e]);
                t = fmaxf(t, __shfl_xor(t, 1, 64));
                if (s == 13 && n >= 12) t = 0.0f;
                colsum[py][e] += t;
                const int oc = g * 4 + e;
                if (s == 0) {
                    const float c0 = GSHFL(t, 0), c1 = GSHFL(t, 2);
                    const float c2 = GSHFL(t, 4), c3 = GSHFL(t, 6);
                    const float S1 = c0, S2 = S1 + c1, S3 = S2 + c2, S4 = S3 + c3;
                    const float sv = (n == 0) ? S1 : (n == 1) ? S2
                                   : (n == 2) ? S3 : S4;
                    if (n < 4 && oc < C1) edgeLo[py][oc][n] = sv;
                }
                if (s == 13) {
                    const float d109 = GSHFL(t, 10), d108 = GSHFL(t, 8);
                    const float d107 = GSHFL(t, 6),  d106 = GSHFL(t, 4);
                    const float U1 = d109, U2 = U1 + d108, U3 = U2 + d107,
                                U4 = U3 + d106;
                    const float uv = (n == 0) ? U1 : (n == 1) ? U2
                                   : (n == 2) ? U3 : U4;
                    if (n < 4 && oc < C1) edgeHi[py][oc][n] = uv;
                }
            }
        }
    }
    #pragma unroll
    for (int py = 0; py < 4; ++py) {
        #pragma unroll
        for (int e = 0; e < 4; ++e) {
            float v = colsum[py][e];
            v += __shfl_xor(v, 2, 64);
            v += __shfl_xor(v, 4, 64);
            v += __shfl_xor(v, 8, 64);
            const int oc = g * 4 + e;
            if (n == 0 && oc < C1) rowR[wid][oc][py] = v;
        }
    }
    __syncthreads();
    if (tid < 150) {
        const int oc = tid / 25;
        const int rem = tid - oc * 25;
        const int ky = rem / 5, kx = rem - ky * 5;
        float total = 0.0f;
        #pragma unroll
        for (int py = 0; py < 4; ++py) {
            const int y = chunk * 4 + py;
            const bool valid = (y < P1) && ((unsigned)(y - ky) <= 105u);
            float v = rowR[0][oc][py] + rowR[1][oc][py] + rowR[2][oc][py]
                    + rowR[3][oc][py] + rowR[4][oc][py] + rowR[5][oc][py]
                    + rowR[6][oc][py];
            if (kx > 0) v -= edgeLo[py][oc][kx - 1];
            if (kx < 4) v -= edgeHi[py][oc][3 - kx];
            total += valid ? v : 0.0f;
        }
        partial[((size_t)b * NCHUNK + chunk) * PSTRIDE + tid] = total;
    }
}

__global__ __launch_bounds__(256) void k2_head(
    const float* __restrict__ partial, const float* __restrict__ w2,
    const float* __restrict__ b2, const float* __restrict__ fc1w,
    const float* __restrict__ fc1b, const float* __restrict__ fc2w,
    const float* __restrict__ fc2b, float* __restrict__ wt_ws,
    float* __restrict__ out)
{
    const int b = blockIdx.x;
    const int tid = threadIdx.x;
    __shared__ float wsb[150];
    __shared__ float sfeat[16];
    __shared__ float sh[8];

    if (tid < 150) {
        const float* p = partial + (size_t)b * NCHUNK * PSTRIDE + tid;
        float s = 0.0f;
        #pragma unroll
        for (int c = 0; c < NCHUNK; ++c) s += p[c * PSTRIDE];
        wsb[tid] = s;
    }
    __syncthreads();
    if (tid < 16) {
        float s = 0.0f;
        for (int j = 0; j < 150; ++j) s += w2[tid * 150 + j] * wsb[j];
        sfeat[tid] = b2[tid] + s * (1.0f / (float)NVALID);
    }
    __syncthreads();
    if (tid < 8) {
        float s = fc1b[tid];
        #pragma unroll
        for (int j = 0; j < 16; ++j) s += fc1w[tid * 16 + j] * sfeat[j];
        sh[tid] = fmaxf(s, 0.0f);
    }
    __syncthreads();
    if (tid < 2) {
        float s = fc2b[tid];
        #pragma unroll
        for (int j = 0; j < 8; ++j) s += fc2w[tid * 8 + j] * sh[j];
        float sig = (s >= 0.0f) ? (1.0f / (1.0f + expf(-s)))
                                : (expf(s) / (1.0f + expf(s)));
        const float wgt = 5.0f * sig;
        wt_ws[b * 2 + tid] = wgt;
        out[POOLED_SIZE + b * 2 + tid] = wgt;
    }
}

__global__ __launch_bounds__(640) void k3_sample_pool_nchw(
    const float* __restrict__ x, const float* __restrict__ ltp,
    const float* __restrict__ wt, float* __restrict__ out)
{
    __shared__ float part[3 * Wg];
    const int L = blockIdx.x;
    const int q = L >> 3;
    const int h = q & 31;
    const int b = (L & 7) + 8 * (q >> 5);
    const int tid = threadIdx.x;

    const float w0 = wt[b * 2 + 0];
    const float w1 = wt[b * 2 + 1];
    const float l0 = ltp[b * 2 + 0];
    const float l1 = ltp[b * 2 + 1];
    const float start = logf(0.01f * w0);
    const float stop  = logf(0.6f  * w1);
    const float dr = stop - start;
    const float angle = 6.283185307179586f * (float)tid / (float)Wg;
    const float sn = __sinf(angle);
    const float cs = __cosf(angle);
    const float* xb = x + (size_t)b * Cn * PLANE;

    float acc0 = 0.0f, acc1 = 0.0f, acc2 = 0.0f;
    #pragma unroll
    for (int i = 0; i < UPR; ++i) {
        const float ri = __expf(start + dr * ((float)(h * UPR + i)
                                              * (1.0f / (float)(Hg - 1))));
        int x0, y0; float wx, wy;
        sample_coords(ri * sn + l0, ri * cs + l1, x0, y0, wx, wy);
        const float wx0 = 1.0f - wx, wy0 = 1.0f - wy;
        const float w00 = wx0 * wy0, w01 = wx * wy0;
        const float w10 = wx0 * wy,  w11 = wx * wy;
        const int o00 = y0 * IMG + x0;
        acc0 += w00*xb[o00] + w01*xb[o00+1] + w10*xb[o00+IMG] + w11*xb[o00+IMG+1];
        const float* x1p = xb + PLANE;
        acc1 += w00*x1p[o00] + w01*x1p[o00+1] + w10*x1p[o00+IMG] + w11*x1p[o00+IMG+1];
        const float* x2p = xb + 2 * PLANE;
        acc2 += w00*x2p[o00] + w01*x2p[o00+1] + w10*x2p[o00+IMG] + w11*x2p[o00+IMG+1];
    }
    part[0 * Wg + tid] = acc0;
    part[1 * Wg + tid] = acc1;
    part[2 * Wg + tid] = acc2;
    __syncthreads();

    if (tid < Cn * Ww) {
        const int c = tid / Ww;
        const int w = tid % Ww;
        const float* p = part + c * Wg + w * UPT;
        float s = 0.0f;
        #pragma unroll
        for (int j = 0; j < UPT; ++j) s += p[j];
        out[(((size_t)b * Cn + c) * Hh + h) * Ww + w] = s * (1.0f / (UPR * UPT));
    }
}

// -------------------------------------------------------------------------
extern "C" void kernel_launch(void* const* d_in, const int* in_sizes, int n_in,
                              void* d_out, int out_size, void* d_ws, size_t ws_size,
                              hipStream_t stream) {
    const float* x       = (const float*)d_in[0];
    const float* ltp     = (const float*)d_in[1];
    const float* conv1_w = (const float*)d_in[2];
    const float* conv1_b = (const float*)d_in[3];
    const float* conv2_w = (const float*)d_in[4];
    const float* conv2_b = (const float*)d_in[5];
    const float* fc1_w   = (const float*)d_in[6];
    const float* fc1_b   = (const float*)d_in[7];
    const float* fc2_w   = (const float*)d_in[8];
    const float* fc2_b   = (const float*)d_in[9];
    float* out = (float*)d_out;

    const int do_pack = (ws_size >= WS_NEEDED) ? 1 : 0;

    float* part_ws = (float*)d_ws;                  // B*28*PSTRIDE
    float* wt_ws   = part_ws + PART_FLOATS;         // B*2 (fallback only)
    u16*   af      = (u16*)(part_ws + AF_OFF_F);    // 5*64*8 f16
    u16*   x4h     = (u16*)(part_ws + X4H_OFF_F);   // 16B-aligned

    if (do_pack) {
        k0_prep<<<dim3(1), dim3(64), 0, stream>>>(conv1_w, af);
        kA_pack<<<dim3(Bn * PLANE / 4 / 256), dim3(256), 0, stream>>>(x, x4h);
        kB_conv<<<dim3(Bn, NCHUNK), dim3(TPB1), 0, stream>>>(
            x4h, af, conv1_b, part_ws);
        k3_fused_head<<<dim3(Hh * Bn), dim3(Wg), 0, stream>>>(
            x4h, ltp, part_ws, conv2_w, conv2_b,
            fc1_w, fc1_b, fc2_w, fc2_b, out);
    } else {
        k1_legacy<<<dim3(Bn, NCHUNK), dim3(TPB1), 0, stream>>>(
            x, conv1_w, conv1_b, part_ws);
        k2_head<<<dim3(Bn), dim3(256), 0, stream>>>(part_ws, conv2_w, conv2_b,
                                                    fc1_w, fc1_b, fc2_w, fc2_b,
                                                    wt_ws, out);
        k3_sample_pool_nchw<<<dim3(Hh * Bn), dim3(Wg), 0, stream>>>(
            x, ltp, wt_ws, out);
    }
}